// Round 12
// baseline (653.494 us; speedup 1.0000x reference)
//
#include <hip/hip_runtime.h>
#include <stdint.h>
#include <stddef.h>

#define D0 4096
#define D1 1024
#define NOUT 1000
#define NB 64
#define PD0 4352   // 8-aligned, zero-padded bucket storage
#define PD1 1264

// ---------------------------------------------------------------------------
// Compile-time fp32-faithful spike pattern, N in [0,32] -> 32-bit cycle mask.
// Replicates runtime fp32 semantics EXACTLY: spacing = fl32(32/N), spike at c
// iff fmodf(c, spacing) < 1.  (Integer shortcut is NOT equivalent.)
// ---------------------------------------------------------------------------
constexpr uint32_t spike_pattern_ct(int N) {
  if (N <= 0) return 0u;
  if (N >= 32) return 0xFFFFFFFFu;
  float sp = 32.0f / (float)N;
  uint32_t m = 0;
  for (int c = 0; c < 32; ++c) {
    double q = (double)c / (double)sp;
    int n = (int)q;                       // trunc, q >= 0
    double r = (double)c - (double)n * (double)sp;   // == fmodf(c, sp), exact
    if (r < 1.0) m |= (1u << c);
  }
  return m;
}

// ---------------------------------------------------------------------------
// Transpose w0 (4096x4096) -> w0T[j][o].  float4 on both global sides.
// ---------------------------------------------------------------------------
__global__ void transpose_w0_k(const float* __restrict__ w, float* __restrict__ wt) {
  __shared__ float tile[32][33];
  int j0 = blockIdx.x * 32;
  int o0 = blockIdx.y * 32;
  int tx = threadIdx.x, ty = threadIdx.y;
  float4 v = *reinterpret_cast<const float4*>(&w[(size_t)(o0 + ty) * D0 + j0 + 4 * tx]);
  tile[ty][4 * tx + 0] = v.x;
  tile[ty][4 * tx + 1] = v.y;
  tile[ty][4 * tx + 2] = v.z;
  tile[ty][4 * tx + 3] = v.w;
  __syncthreads();
  float4 u;
  u.x = tile[4 * tx + 0][ty];
  u.y = tile[4 * tx + 1][ty];
  u.z = tile[4 * tx + 2][ty];
  u.w = tile[4 * tx + 3][ty];
  *reinterpret_cast<float4*>(&wt[(size_t)(j0 + ty) * D0 + o0 + 4 * tx]) = u;
}

// Transpose w2 (1000x1024) -> w2T[j][o], o padded to 1024 with zeros.
__global__ void transpose_w2_k(const float* __restrict__ w, float* __restrict__ wt) {
  __shared__ float tile[32][33];
  int j0 = blockIdx.x * 32;
  int o0 = blockIdx.y * 32;
  int tx = threadIdx.x, ty = threadIdx.y;
  int o = o0 + ty;
  float4 v = make_float4(0.f, 0.f, 0.f, 0.f);
  if (o < NOUT) v = *reinterpret_cast<const float4*>(&w[(size_t)o * D1 + j0 + 4 * tx]);
  tile[ty][4 * tx + 0] = v.x;
  tile[ty][4 * tx + 1] = v.y;
  tile[ty][4 * tx + 2] = v.z;
  tile[ty][4 * tx + 3] = v.w;
  __syncthreads();
  float4 u;
  u.x = tile[4 * tx + 0][ty];
  u.y = tile[4 * tx + 1][ty];
  u.z = tile[4 * tx + 2][ty];
  u.w = tile[4 * tx + 3][ty];
  *reinterpret_cast<float4*>(&wt[(size_t)(j0 + ty) * D1 + o0 + 4 * tx]) = u;
}

// ---------------------------------------------------------------------------
// Per-batch counting sort with 8-ALIGNED bucket starts (pad slots = 0 so a
// masked tail group gathers row 0 and masks it — no OOB, no serial tail).
// starts layout per batch: [0..33] aligned starts (34), [34..66] true lens.
// prep_sort0: key = rint(x[b][idx0[j]]*32) (compute_N0 fused).
// ---------------------------------------------------------------------------
__global__ void prep_sort0_k(const float* __restrict__ x, const int* __restrict__ idx0,
                             uint16_t* __restrict__ perm, int* __restrict__ starts) {
  __shared__ int keys[D0];
  __shared__ int hist[33];
  __shared__ int base[34];
  __shared__ int cursor[33];
  int b = blockIdx.x;
  int tid = threadIdx.x;
  if (tid < 33) hist[tid] = 0;
  for (int p = tid; p < PD0; p += 256) perm[(size_t)b * PD0 + p] = 0;
  __syncthreads();
  for (int j = tid; j < D0; j += 256) {
    int k = (int)rintf(x[b * D0 + idx0[j]] * 32.0f);
    keys[j] = k;
    atomicAdd(&hist[k], 1);
  }
  __syncthreads();
  if (tid == 0) {
    int s = 0;
    for (int k = 0; k < 33; ++k) {
      base[k] = s; cursor[k] = s;
      s = (s + hist[k] + 7) & ~7;        // 8-aligned next start
    }
    base[33] = s;
  }
  __syncthreads();
  if (tid < 34) starts[b * 68 + tid] = base[tid];
  if (tid < 33) starts[b * 68 + 34 + tid] = hist[tid];
  for (int j = tid; j < D0; j += 256) {
    int k = keys[j];
    int pos = atomicAdd(&cursor[k], 1);
    perm[(size_t)b * PD0 + pos] = (uint16_t)j;
  }
}

// prep_sort1: key from pooled spike counts (pool_encode fused).
__global__ void prep_sort1_k(const int* __restrict__ k0, const int* __restrict__ idx1,
                             const int* __restrict__ idx2,
                             uint16_t* __restrict__ perm, int* __restrict__ starts) {
  __shared__ int keys[D1];
  __shared__ int hist[33];
  __shared__ int base[34];
  __shared__ int cursor[33];
  int b = blockIdx.x;
  int tid = threadIdx.x;
  if (tid < 33) hist[tid] = 0;
  for (int p = tid; p < PD1; p += 256) perm[(size_t)b * PD1 + p] = 0;
  __syncthreads();
  for (int j = tid; j < D1; j += 256) {
    int q2 = idx2[j];
    int c = q2 >> 4;
    int h2 = (q2 >> 2) & 3;
    int w2 = q2 & 3;
    int cnt = 0;
#pragma unroll
    for (int dh = 0; dh < 2; ++dh)
#pragma unroll
      for (int dw = 0; dw < 2; ++dw) {
        int q = c * 64 + (2 * h2 + dh) * 8 + (2 * w2 + dw);
        cnt += k0[b * D0 + idx1[q]];
      }
    int k = (int)rintf((float)cnt * 0.25f);
    keys[j] = k;
    atomicAdd(&hist[k], 1);
  }
  __syncthreads();
  if (tid == 0) {
    int s = 0;
    for (int k = 0; k < 33; ++k) {
      base[k] = s; cursor[k] = s;
      s = (s + hist[k] + 7) & ~7;
    }
    base[33] = s;
  }
  __syncthreads();
  if (tid < 34) starts[b * 68 + tid] = base[tid];
  if (tid < 33) starts[b * 68 + 34 + tid] = hist[tid];
  for (int j = tid; j < D1; j += 256) {
    int k = keys[j];
    int pos = atomicAdd(&cursor[k], 1);
    perm[(size_t)b * PD1 + pos] = (uint16_t)j;
  }
}

// ---------------------------------------------------------------------------
// LIF core, bucket decomposition, fp64-exact.
//
// Round-10 evidence: dur 213us vs max(VALU 126, L2 125) ideal; WRITE_SIZE
// stuck at 27 MB (unexplained — scratch suspect: bs[] array), VALU overhead
// ~2x essential (rfl + 1-float-per-gather issue cost).
//
// Round-12 (= round-11 with the ## token-pasting fix: (F##0).x, since 0.x
// lexes as one pp-number token):
//  * 16 wave-groups, 2 buckets each (k = g+1, g+17; bucket sizes ~uniform
//    ~128 -> balanced).  One wave covers the 128-col tile with 2 adjacent
//    cols per thread.
//  * float2 gathers (global_load_dwordx2, 512 B/wave-gather): halves gather
//    instruction count, rfl count, and loop iterations per element; doubles
//    in-flight bytes at the same pipeline depth.
//  * NO bs[] array: each bucket's 2-col fp64 sum publishes straight to
//    cshare as a 16 B store when the bucket completes (removes the runtime-
//    indexed-array scratch candidate — WRITE_SIZE is the diagnostic).
//  * Scan: wave 0, 2 cols/lane, double2 LDS reads.
// ---------------------------------------------------------------------------
template <int D, int PD, int OSTRIDE>
__launch_bounds__(1024, 8)
__global__ void lif_core_k(const float* __restrict__ wt, const uint16_t* __restrict__ perm,
                           const int* __restrict__ starts, const float* __restrict__ thr_p,
                           int* __restrict__ cnt_out) {
  __shared__ double cshare[32][128];   // 32 KB: bucket k -> row ((k-1)&15)*2+((k-1)>>4)
  __shared__ uint16_t permS[PD];
  int tid = threadIdx.x;
  int b = blockIdx.y;
  int lane = tid & 63;
  int g = __builtin_amdgcn_readfirstlane(tid >> 6);   // wave 0..15, uniform

  // Stage this batch's (aligned, zero-padded) perm into LDS.
  {
    const ushort2* p2 = reinterpret_cast<const ushort2*>(perm + (size_t)b * PD);
    ushort2* s2 = reinterpret_cast<ushort2*>(permS);
    for (int i = tid; i < PD / 2; i += 1024) s2[i] = p2[i];
  }
  __syncthreads();

  const int* stA = starts + b * 68;        // aligned starts[34]
  const int* stL = starts + b * 68 + 34;   // true lens[33]
  double th = (double)thr_p[0];
  int o = (blockIdx.x + gridDim.x * blockIdx.z) * 128 + lane * 2;

#define RDIDX(P) do { \
    const uint32_t* _q = reinterpret_cast<const uint32_t*>(permS + ip); \
    uint32_t _w0 = _q[0], _w1 = _q[1], _w2 = _q[2], _w3 = _q[3]; \
    uint32_t _s0 = __builtin_amdgcn_readfirstlane(_w0); \
    uint32_t _s1 = __builtin_amdgcn_readfirstlane(_w1); \
    uint32_t _s2 = __builtin_amdgcn_readfirstlane(_w2); \
    uint32_t _s3 = __builtin_amdgcn_readfirstlane(_w3); \
    P##0 = _s0 & 0xffffu; P##1 = _s0 >> 16; \
    P##2 = _s1 & 0xffffu; P##3 = _s1 >> 16; \
    P##4 = _s2 & 0xffffu; P##5 = _s2 >> 16; \
    P##6 = _s3 & 0xffffu; P##7 = _s3 >> 16; \
    ip += 8; \
  } while (0)

#define GATHER(F, P) do { \
    F##0 = *reinterpret_cast<const float2*>(&wt[(size_t)P##0 * OSTRIDE + o]); \
    F##1 = *reinterpret_cast<const float2*>(&wt[(size_t)P##1 * OSTRIDE + o]); \
    F##2 = *reinterpret_cast<const float2*>(&wt[(size_t)P##2 * OSTRIDE + o]); \
    F##3 = *reinterpret_cast<const float2*>(&wt[(size_t)P##3 * OSTRIDE + o]); \
    F##4 = *reinterpret_cast<const float2*>(&wt[(size_t)P##4 * OSTRIDE + o]); \
    F##5 = *reinterpret_cast<const float2*>(&wt[(size_t)P##5 * OSTRIDE + o]); \
    F##6 = *reinterpret_cast<const float2*>(&wt[(size_t)P##6 * OSTRIDE + o]); \
    F##7 = *reinterpret_cast<const float2*>(&wt[(size_t)P##7 * OSTRIDE + o]); \
  } while (0)

#define ACC8(F) do { \
    a0x += (double)(F##0).x; a0y += (double)(F##0).y; \
    a1x += (double)(F##1).x; a1y += (double)(F##1).y; \
    a2x += (double)(F##2).x; a2y += (double)(F##2).y; \
    a3x += (double)(F##3).x; a3y += (double)(F##3).y; \
    a0x += (double)(F##4).x; a0y += (double)(F##4).y; \
    a1x += (double)(F##5).x; a1y += (double)(F##5).y; \
    a2x += (double)(F##6).x; a2y += (double)(F##6).y; \
    a3x += (double)(F##7).x; a3y += (double)(F##7).y; \
  } while (0)

#pragma unroll
  for (int i = 0; i < 2; ++i) {
    int k = g + 1 + 16 * i;            // this wave's i-th bucket (1..32)
    int row = g * 2 + i;               // == ((k-1)&15)*2 + ((k-1)>>4)
    int hs0 = __builtin_amdgcn_readfirstlane(stA[k]);
    int len = __builtin_amdgcn_readfirstlane(stL[k]);
    double a0x = 0.0, a0y = 0.0, a1x = 0.0, a1y = 0.0;
    double a2x = 0.0, a2y = 0.0, a3x = 0.0, a3y = 0.0;
    if (len > 0) {                     // scalar branch
      int ip = hs0;
      int ng = len >> 3, rem = len & 7;
      uint32_t pA0, pA1, pA2, pA3, pA4, pA5, pA6, pA7;
      uint32_t pB0, pB1, pB2, pB3, pB4, pB5, pB6, pB7;
      float2 fA0, fA1, fA2, fA3, fA4, fA5, fA6, fA7;
      float2 fB0, fB1, fB2, fB3, fB4, fB5, fB6, fB7;
      if (ng > 0) {
        RDIDX(pA); GATHER(fA, pA);
        int gg = 1;
        for (; gg + 1 < ng; gg += 2) {
          RDIDX(pB); GATHER(fB, pB);   // next group in flight...
          ACC8(fA);                    // ...while this one accumulates
          RDIDX(pA); GATHER(fA, pA);
          ACC8(fB);
        }
        if (gg < ng) {
          RDIDX(pB); GATHER(fB, pB);
          ACC8(fA);
          ACC8(fB);
        } else {
          ACC8(fA);
        }
      }
      if (rem) {                       // aligned masked tail (pad reads row 0)
        RDIDX(pA); GATHER(fA, pA);
        a0x += (double)fA0.x; a0y += (double)fA0.y;      // rem >= 1
        if (rem > 1) { a1x += (double)fA1.x; a1y += (double)fA1.y; }
        if (rem > 2) { a2x += (double)fA2.x; a2y += (double)fA2.y; }
        if (rem > 3) { a3x += (double)fA3.x; a3y += (double)fA3.y; }
        if (rem > 4) { a0x += (double)fA4.x; a0y += (double)fA4.y; }
        if (rem > 5) { a1x += (double)fA5.x; a1y += (double)fA5.y; }
        if (rem > 6) { a2x += (double)fA6.x; a2y += (double)fA6.y; }
      }
    }
    // Publish this bucket's 2-col sum directly (no bs[] array -> no scratch).
    cshare[row][lane * 2 + 0] = (a0x + a1x) + (a2x + a3x);
    cshare[row][lane * 2 + 1] = (a0y + a1y) + (a2y + a3y);
  }
  __syncthreads();

  if (g == 0) {
    // Membrane scan, 2 cols/lane: 528 compile-time-selected double2 terms.
    double m0 = 0.0, m1 = 0.0;
    int c0 = 0, c1 = 0;
#pragma unroll
    for (int t = 0; t < 32; ++t) {
#pragma unroll
      for (int k = 1; k <= 32; ++k)
        if ((spike_pattern_ct(k) >> t) & 1u) {
          const int row = ((k - 1) & 15) * 2 + ((k - 1) >> 4);
          const double2 v = *reinterpret_cast<const double2*>(&cshare[row][lane * 2]);
          m0 += v.x; m1 += v.y;
        }
      if (m0 > th) { m0 -= th; ++c0; }   // strict: threshold < memb
      if (m1 > th) { m1 -= th; ++c1; }
    }
    cnt_out[(size_t)b * OSTRIDE + o + 0] = c0;
    cnt_out[(size_t)b * OSTRIDE + o + 1] = c1;
  }

#undef RDIDX
#undef GATHER
#undef ACC8
}

__global__ void write_out_k(const int* __restrict__ cnt2, const int* __restrict__ idx_out,
                            float* __restrict__ out) {
  int i = blockIdx.x * 256 + threadIdx.x;
  if (i >= NB * NOUT) return;
  int b = i / NOUT;
  int r = i - b * NOUT;
  out[i] = (float)cnt2[b * D1 + idx_out[r]];
}

// ---------------------------------------------------------------------------
extern "C" void kernel_launch(void* const* d_in, const int* in_sizes, int n_in,
                              void* d_out, int out_size, void* d_ws, size_t ws_size,
                              hipStream_t stream) {
  const float* x      = (const float*)d_in[0];
  const float* w0     = (const float*)d_in[1];
  const float* t0     = (const float*)d_in[2];
  const float* w2     = (const float*)d_in[3];
  const float* t2     = (const float*)d_in[4];
  const int*   idx0   = (const int*)d_in[5];
  const int*   idx1   = (const int*)d_in[6];
  const int*   idx2   = (const int*)d_in[7];
  const int*   idx_out= (const int*)d_in[8];
  float* out = (float*)d_out;

  char* ws = (char*)d_ws;
  float*    w0T    = (float*)ws;    ws += (size_t)D0 * D0 * 4;   // 64 MB
  float*    w2T    = (float*)ws;    ws += (size_t)D1 * D1 * 4;   // 4 MB
  uint16_t* perm0  = (uint16_t*)ws; ws += (size_t)NB * PD0 * 2;
  uint16_t* perm2  = (uint16_t*)ws; ws += (size_t)NB * PD1 * 2;
  int*      k0     = (int*)ws;      ws += (size_t)NB * D0 * 4;
  int*      cnt2   = (int*)ws;      ws += (size_t)NB * D1 * 4;
  int*      starts0= (int*)ws;      ws += (size_t)NB * 68 * 4;
  int*      starts2= (int*)ws;      ws += (size_t)NB * 68 * 4;

  transpose_w0_k<<<dim3(D0 / 32, D0 / 32), dim3(8, 32), 0, stream>>>(w0, w0T);
  transpose_w2_k<<<dim3(D1 / 32, D1 / 32), dim3(8, 32), 0, stream>>>(w2, w2T);
  prep_sort0_k<<<NB, 256, 0, stream>>>(x, idx0, perm0, starts0);
  // grid (8, NB, 4): 2048 blocks, 512 resident (2/CU, 32 waves/CU).  XCD x
  // streams 128-col (2 MB) slices z=0..3 sequentially — half-L2 working set.
  lif_core_k<D0, PD0, D0><<<dim3(8, NB, 4), 1024, 0, stream>>>(w0T, perm0, starts0, t0, k0);
  prep_sort1_k<<<NB, 256, 0, stream>>>(k0, idx1, idx2, perm2, starts2);
  lif_core_k<D1, PD1, D1><<<dim3(8, NB, 1), 1024, 0, stream>>>(w2T, perm2, starts2, t2, cnt2);
  write_out_k<<<(NB * NOUT + 255) / 256, 256, 0, stream>>>(cnt2, idx_out, out);
}

// Round 14
// 398.699 us; speedup vs baseline: 1.6391x; 1.6391x over previous
//
#include <hip/hip_runtime.h>
#include <stdint.h>
#include <stddef.h>

#define D0 4096
#define D1 1024
#define NOUT 1000
#define NB 64
#define PD0 4352   // 8-aligned, zero-padded bucket storage
#define PD1 1264

// ---------------------------------------------------------------------------
// Compile-time fp32-faithful spike pattern, N in [0,32] -> 32-bit cycle mask.
// Replicates runtime fp32 semantics EXACTLY: spacing = fl32(32/N), spike at c
// iff fmodf(c, spacing) < 1.  (Integer shortcut is NOT equivalent.)
// ---------------------------------------------------------------------------
constexpr uint32_t spike_pattern_ct(int N) {
  if (N <= 0) return 0u;
  if (N >= 32) return 0xFFFFFFFFu;
  float sp = 32.0f / (float)N;
  uint32_t m = 0;
  for (int c = 0; c < 32; ++c) {
    double q = (double)c / (double)sp;
    int n = (int)q;                       // trunc, q >= 0
    double r = (double)c - (double)n * (double)sp;   // == fmodf(c, sp), exact
    if (r < 1.0) m |= (1u << c);
  }
  return m;
}

// ---------------------------------------------------------------------------
// Transpose w0 (4096x4096) -> w0T[j][o].  float4 on both global sides.
// ---------------------------------------------------------------------------
__global__ void transpose_w0_k(const float* __restrict__ w, float* __restrict__ wt) {
  __shared__ float tile[32][33];
  int j0 = blockIdx.x * 32;
  int o0 = blockIdx.y * 32;
  int tx = threadIdx.x, ty = threadIdx.y;
  float4 v = *reinterpret_cast<const float4*>(&w[(size_t)(o0 + ty) * D0 + j0 + 4 * tx]);
  tile[ty][4 * tx + 0] = v.x;
  tile[ty][4 * tx + 1] = v.y;
  tile[ty][4 * tx + 2] = v.z;
  tile[ty][4 * tx + 3] = v.w;
  __syncthreads();
  float4 u;
  u.x = tile[4 * tx + 0][ty];
  u.y = tile[4 * tx + 1][ty];
  u.z = tile[4 * tx + 2][ty];
  u.w = tile[4 * tx + 3][ty];
  *reinterpret_cast<float4*>(&wt[(size_t)(j0 + ty) * D0 + o0 + 4 * tx]) = u;
}

// Transpose w2 (1000x1024) -> w2T[j][o], o padded to 1024 with zeros.
__global__ void transpose_w2_k(const float* __restrict__ w, float* __restrict__ wt) {
  __shared__ float tile[32][33];
  int j0 = blockIdx.x * 32;
  int o0 = blockIdx.y * 32;
  int tx = threadIdx.x, ty = threadIdx.y;
  int o = o0 + ty;
  float4 v = make_float4(0.f, 0.f, 0.f, 0.f);
  if (o < NOUT) v = *reinterpret_cast<const float4*>(&w[(size_t)o * D1 + j0 + 4 * tx]);
  tile[ty][4 * tx + 0] = v.x;
  tile[ty][4 * tx + 1] = v.y;
  tile[ty][4 * tx + 2] = v.z;
  tile[ty][4 * tx + 3] = v.w;
  __syncthreads();
  float4 u;
  u.x = tile[4 * tx + 0][ty];
  u.y = tile[4 * tx + 1][ty];
  u.z = tile[4 * tx + 2][ty];
  u.w = tile[4 * tx + 3][ty];
  *reinterpret_cast<float4*>(&wt[(size_t)(j0 + ty) * D1 + o0 + 4 * tx]) = u;
}

// ---------------------------------------------------------------------------
// Per-batch counting sort with 8-ALIGNED bucket starts (pad slots = 0 so a
// masked tail group gathers row 0 and masks it — no OOB, no serial tail).
// starts layout per batch: [0..33] aligned starts (34), [34..66] true lens.
// prep_sort0: key = rint(x[b][idx0[j]]*32) (compute_N0 fused).
// ---------------------------------------------------------------------------
__global__ void prep_sort0_k(const float* __restrict__ x, const int* __restrict__ idx0,
                             uint16_t* __restrict__ perm, int* __restrict__ starts) {
  __shared__ int keys[D0];
  __shared__ int hist[33];
  __shared__ int base[34];
  __shared__ int cursor[33];
  int b = blockIdx.x;
  int tid = threadIdx.x;
  if (tid < 33) hist[tid] = 0;
  for (int p = tid; p < PD0; p += 256) perm[(size_t)b * PD0 + p] = 0;
  __syncthreads();
  for (int j = tid; j < D0; j += 256) {
    int k = (int)rintf(x[b * D0 + idx0[j]] * 32.0f);
    keys[j] = k;
    atomicAdd(&hist[k], 1);
  }
  __syncthreads();
  if (tid == 0) {
    int s = 0;
    for (int k = 0; k < 33; ++k) {
      base[k] = s; cursor[k] = s;
      s = (s + hist[k] + 7) & ~7;        // 8-aligned next start
    }
    base[33] = s;
  }
  __syncthreads();
  if (tid < 34) starts[b * 68 + tid] = base[tid];
  if (tid < 33) starts[b * 68 + 34 + tid] = hist[tid];
  for (int j = tid; j < D0; j += 256) {
    int k = keys[j];
    int pos = atomicAdd(&cursor[k], 1);
    perm[(size_t)b * PD0 + pos] = (uint16_t)j;
  }
}

// prep_sort1: key from pooled spike counts (pool_encode fused).
__global__ void prep_sort1_k(const int* __restrict__ k0, const int* __restrict__ idx1,
                             const int* __restrict__ idx2,
                             uint16_t* __restrict__ perm, int* __restrict__ starts) {
  __shared__ int keys[D1];
  __shared__ int hist[33];
  __shared__ int base[34];
  __shared__ int cursor[33];
  int b = blockIdx.x;
  int tid = threadIdx.x;
  if (tid < 33) hist[tid] = 0;
  for (int p = tid; p < PD1; p += 256) perm[(size_t)b * PD1 + p] = 0;
  __syncthreads();
  for (int j = tid; j < D1; j += 256) {
    int q2 = idx2[j];
    int c = q2 >> 4;
    int h2 = (q2 >> 2) & 3;
    int w2 = q2 & 3;
    int cnt = 0;
#pragma unroll
    for (int dh = 0; dh < 2; ++dh)
#pragma unroll
      for (int dw = 0; dw < 2; ++dw) {
        int q = c * 64 + (2 * h2 + dh) * 8 + (2 * w2 + dw);
        cnt += k0[b * D0 + idx1[q]];
      }
    int k = (int)rintf((float)cnt * 0.25f);
    keys[j] = k;
    atomicAdd(&hist[k], 1);
  }
  __syncthreads();
  if (tid == 0) {
    int s = 0;
    for (int k = 0; k < 33; ++k) {
      base[k] = s; cursor[k] = s;
      s = (s + hist[k] + 7) & ~7;
    }
    base[33] = s;
  }
  __syncthreads();
  if (tid < 34) starts[b * 68 + tid] = base[tid];
  if (tid < 33) starts[b * 68 + 34 + tid] = hist[tid];
  for (int j = tid; j < D1; j += 256) {
    int k = keys[j];
    int pos = atomicAdd(&cursor[k], 1);
    perm[(size_t)b * PD1 + pos] = (uint16_t)j;
  }
}

// ---------------------------------------------------------------------------
// LIF core, bucket decomposition, fp64-exact.
//
// Round-12 post-mortem: float2 x8-wide overflowed the 64-VGPR cap (32 VGPR
// in-flight data + 16 acc) and the double2 scan hoisted 64 VGPRs of LDS
// values -> 240 MB scratch traffic, 2.2x regression.  REVERTED to round-10
// geometry (proven 213us): grid (8,NB,4) 128-col tiles, 1024 thr, 8 groups
// x 4 buckets (k = 8i+g+1), perm in LDS, masked aligned tails.
//
// Round-13/14 changes on that base (round-13 bench was an infra flake —
// identical resubmit, like round 3 -> 4):
//  * DEPTH-3 gather pipeline (pA/pB/pC, fA/fB/fC rotation).  Round-10 math:
//    VALUBusy 59% at 4 waves/SIMD = ~15% per-wave duty — depth-2 issues the
//    next group only ~100cy before use vs ~250cy L2 latency, so every
//    iteration eats ~150cy of exposed latency.  Depth-3 = ~300cy issue-ahead.
//    Register cost: 24 float + 8 fp64-acc ~= 50 VGPR, fits the 64 cap.
//  * No bs[] array: each bucket's sum publishes straight to cshare (kills
//    one scratch candidate).
//  * Scan reads cshare via a VOLATILE pointer: forbids the 32-double hoist
//    (the other scratch candidate, likely round-10's mystery 27 MB WRITE).
// ---------------------------------------------------------------------------
template <int D, int PD, int OSTRIDE>
__launch_bounds__(1024, 8)
__global__ void lif_core_k(const float* __restrict__ wt, const uint16_t* __restrict__ perm,
                           const int* __restrict__ starts, const float* __restrict__ thr_p,
                           int* __restrict__ cnt_out) {
  __shared__ double cshare[32][128];   // 32 KB: bucket k -> row ((k-1)&7)*4+((k-1)>>3)
  __shared__ uint16_t permS[PD];
  int tid = threadIdx.x;
  int b = blockIdx.y;
  int col = tid & 127;
  int g = __builtin_amdgcn_readfirstlane(tid >> 7);   // group 0..7, wave-uniform

  // Stage this batch's (aligned, zero-padded) perm into LDS.
  {
    const ushort2* p2 = reinterpret_cast<const ushort2*>(perm + (size_t)b * PD);
    ushort2* s2 = reinterpret_cast<ushort2*>(permS);
    for (int i = tid; i < PD / 2; i += 1024) s2[i] = p2[i];
  }
  __syncthreads();

  const int* stA = starts + b * 68;        // aligned starts[34]
  const int* stL = starts + b * 68 + 34;   // true lens[33]
  double th = (double)thr_p[0];
  int o = (blockIdx.x + gridDim.x * blockIdx.z) * 128 + col;

#define RDIDX(P) do { \
    const uint32_t* _q = reinterpret_cast<const uint32_t*>(permS + ip); \
    uint32_t _w0 = _q[0], _w1 = _q[1], _w2 = _q[2], _w3 = _q[3]; \
    uint32_t _s0 = __builtin_amdgcn_readfirstlane(_w0); \
    uint32_t _s1 = __builtin_amdgcn_readfirstlane(_w1); \
    uint32_t _s2 = __builtin_amdgcn_readfirstlane(_w2); \
    uint32_t _s3 = __builtin_amdgcn_readfirstlane(_w3); \
    P##0 = _s0 & 0xffffu; P##1 = _s0 >> 16; \
    P##2 = _s1 & 0xffffu; P##3 = _s1 >> 16; \
    P##4 = _s2 & 0xffffu; P##5 = _s2 >> 16; \
    P##6 = _s3 & 0xffffu; P##7 = _s3 >> 16; \
    ip += 8; \
  } while (0)

#define GATHER(F, P) do { \
    F##0 = wt[(size_t)P##0 * OSTRIDE + o]; \
    F##1 = wt[(size_t)P##1 * OSTRIDE + o]; \
    F##2 = wt[(size_t)P##2 * OSTRIDE + o]; \
    F##3 = wt[(size_t)P##3 * OSTRIDE + o]; \
    F##4 = wt[(size_t)P##4 * OSTRIDE + o]; \
    F##5 = wt[(size_t)P##5 * OSTRIDE + o]; \
    F##6 = wt[(size_t)P##6 * OSTRIDE + o]; \
    F##7 = wt[(size_t)P##7 * OSTRIDE + o]; \
  } while (0)

#define ACC8(F) do { \
    a0 += (double)F##0; a1 += (double)F##1; a2 += (double)F##2; a3 += (double)F##3; \
    a0 += (double)F##4; a1 += (double)F##5; a2 += (double)F##6; a3 += (double)F##7; \
  } while (0)

#pragma unroll
  for (int i = 0; i < 4; ++i) {
    int k = 8 * i + g + 1;             // this group's i-th bucket (1..32)
    int row = g * 4 + i;               // == ((k-1)&7)*4 + ((k-1)>>3)
    int hs0 = __builtin_amdgcn_readfirstlane(stA[k]);
    int len = __builtin_amdgcn_readfirstlane(stL[k]);
    double a0 = 0.0, a1 = 0.0, a2 = 0.0, a3 = 0.0;
    if (len > 0) {                     // scalar branch
      int ip = hs0;
      int ng = len >> 3, rem = len & 7;
      uint32_t pA0, pA1, pA2, pA3, pA4, pA5, pA6, pA7;
      uint32_t pB0, pB1, pB2, pB3, pB4, pB5, pB6, pB7;
      uint32_t pC0, pC1, pC2, pC3, pC4, pC5, pC6, pC7;
      float fA0, fA1, fA2, fA3, fA4, fA5, fA6, fA7;
      float fB0, fB1, fB2, fB3, fB4, fB5, fB6, fB7;
      float fC0, fC1, fC2, fC3, fC4, fC5, fC6, fC7;
      if (ng >= 2) {
        // Prologue: 2 groups in flight.
        RDIDX(pA); GATHER(fA, pA);
        RDIDX(pB); GATHER(fB, pB);
        int gg = 2;
        // Steady state: 3 groups in flight (~300cy issue-ahead).
        for (; gg + 3 <= ng; gg += 3) {
          RDIDX(pC); GATHER(fC, pC); ACC8(fA);
          RDIDX(pA); GATHER(fA, pA); ACC8(fB);
          RDIDX(pB); GATHER(fB, pB); ACC8(fC);
        }
        int r = ng - gg;               // 0..2 groups left to issue
        if (r == 0) {
          ACC8(fA); ACC8(fB);
        } else if (r == 1) {
          RDIDX(pC); GATHER(fC, pC); ACC8(fA);
          ACC8(fB); ACC8(fC);
        } else {                       // r == 2
          RDIDX(pC); GATHER(fC, pC); ACC8(fA);
          RDIDX(pA); GATHER(fA, pA); ACC8(fB);
          ACC8(fC); ACC8(fA);
        }
      } else if (ng == 1) {
        RDIDX(pA); GATHER(fA, pA); ACC8(fA);
      }
      if (rem) {                       // aligned masked tail (pad reads row 0)
        RDIDX(pA); GATHER(fA, pA);
        a0 += (double)fA0;             // rem >= 1 always here
        if (rem > 1) a1 += (double)fA1;
        if (rem > 2) a2 += (double)fA2;
        if (rem > 3) a3 += (double)fA3;
        if (rem > 4) a0 += (double)fA4;
        if (rem > 5) a1 += (double)fA5;
        if (rem > 6) a2 += (double)fA6;
      }
    }
    // Publish this bucket's sum directly (no bs[] array -> no scratch).
    cshare[row][col] = (a0 + a1) + (a2 + a3);
  }
  __syncthreads();

  if (g == 0) {
    // Membrane scan: 528 compile-time-selected fp64 adds.  VOLATILE LDS
    // reads prevent the compiler hoisting 32 doubles (=64 VGPR -> spill).
    volatile const double* cs = &cshare[0][0];
    double memb = 0.0;
    int cnt = 0;
#pragma unroll
    for (int t = 0; t < 32; ++t) {
#pragma unroll
      for (int k = 1; k <= 32; ++k)
        if ((spike_pattern_ct(k) >> t) & 1u) {
          const int row = ((k - 1) & 7) * 4 + ((k - 1) >> 3);
          memb += cs[row * 128 + col];
        }
      if (memb > th) { memb -= th; ++cnt; }   // strict: threshold < memb
    }
    cnt_out[(size_t)b * OSTRIDE + o] = cnt;
  }

#undef RDIDX
#undef GATHER
#undef ACC8
}

__global__ void write_out_k(const int* __restrict__ cnt2, const int* __restrict__ idx_out,
                            float* __restrict__ out) {
  int i = blockIdx.x * 256 + threadIdx.x;
  if (i >= NB * NOUT) return;
  int b = i / NOUT;
  int r = i - b * NOUT;
  out[i] = (float)cnt2[b * D1 + idx_out[r]];
}

// ---------------------------------------------------------------------------
extern "C" void kernel_launch(void* const* d_in, const int* in_sizes, int n_in,
                              void* d_out, int out_size, void* d_ws, size_t ws_size,
                              hipStream_t stream) {
  const float* x      = (const float*)d_in[0];
  const float* w0     = (const float*)d_in[1];
  const float* t0     = (const float*)d_in[2];
  const float* w2     = (const float*)d_in[3];
  const float* t2     = (const float*)d_in[4];
  const int*   idx0   = (const int*)d_in[5];
  const int*   idx1   = (const int*)d_in[6];
  const int*   idx2   = (const int*)d_in[7];
  const int*   idx_out= (const int*)d_in[8];
  float* out = (float*)d_out;

  char* ws = (char*)d_ws;
  float*    w0T    = (float*)ws;    ws += (size_t)D0 * D0 * 4;   // 64 MB
  float*    w2T    = (float*)ws;    ws += (size_t)D1 * D1 * 4;   // 4 MB
  uint16_t* perm0  = (uint16_t*)ws; ws += (size_t)NB * PD0 * 2;
  uint16_t* perm2  = (uint16_t*)ws; ws += (size_t)NB * PD1 * 2;
  int*      k0     = (int*)ws;      ws += (size_t)NB * D0 * 4;
  int*      cnt2   = (int*)ws;      ws += (size_t)NB * D1 * 4;
  int*      starts0= (int*)ws;      ws += (size_t)NB * 68 * 4;
  int*      starts2= (int*)ws;      ws += (size_t)NB * 68 * 4;

  transpose_w0_k<<<dim3(D0 / 32, D0 / 32), dim3(8, 32), 0, stream>>>(w0, w0T);
  transpose_w2_k<<<dim3(D1 / 32, D1 / 32), dim3(8, 32), 0, stream>>>(w2, w2T);
  prep_sort0_k<<<NB, 256, 0, stream>>>(x, idx0, perm0, starts0);
  // grid (8, NB, 4): 2048 blocks, 512 resident (2/CU, 32 waves/CU).  XCD x
  // streams 128-col (2 MB) slices z=0..3 sequentially — half-L2 working set.
  lif_core_k<D0, PD0, D0><<<dim3(8, NB, 4), 1024, 0, stream>>>(w0T, perm0, starts0, t0, k0);
  prep_sort1_k<<<NB, 256, 0, stream>>>(k0, idx1, idx2, perm2, starts2);
  lif_core_k<D1, PD1, D1><<<dim3(8, NB, 1), 1024, 0, stream>>>(w2T, perm2, starts2, t2, cnt2);
  write_out_k<<<(NB * NOUT + 255) / 256, 256, 0, stream>>>(cnt2, idx_out, out);
}